// Round 2
// baseline (3123.440 us; speedup 1.0000x reference)
//
#include <hip/hip_runtime.h>

// MassConservingLSTM_MR — persistent 32-block recurrent kernel, round 4.
// R4 change: eliminate vmcnt pollution of the spin. Pre-spin vmem is ONLY the
// x-prefetch load: the 7 deferred out-stores (HBM ack ~1us) and the featx
// ds_write (whose vmcnt wait dragged all store acks, by in-order vmcnt
// retirement) move to AFTER spin detection, so the poll loop's vmcnt(0) no
// longer serializes on store drains. Slot protocol reverted to R2's compact
// 256-float all-wave polling (measured better than R3's wave0+LDS fanout).

#define T_STEPS 512
#define OUTSZ 8388608ull  // 512*512*32

using bf16v8 = __attribute__((ext_vector_type(8))) short;
using f32v4  = __attribute__((ext_vector_type(4))) float;

__device__ __forceinline__ short f2b(float f) {
  union { float f; unsigned u; } x; x.f = f;
  unsigned r = x.u + 0x7fffu + ((x.u >> 16) & 1u);
  return (short)(r >> 16);
}
__device__ __forceinline__ float rcpf(float x) { return __builtin_amdgcn_rcpf(x); }

__global__ __launch_bounds__(512, 2) void mclstm_persistent(
    const float* __restrict__ g_xm, const float* __restrict__ g_xa,
    const float* __restrict__ g_Wi, const float* __restrict__ g_bi,
    const float* __restrict__ g_Wr, const float* __restrict__ g_br,
    const float* __restrict__ g_Wo, const float* __restrict__ g_bo,
    const float* __restrict__ g_Ws, const float* __restrict__ g_Wrm,
    const float* __restrict__ g_b0, const float* __restrict__ g_lng,
    const float* __restrict__ g_lnb,
    float* __restrict__ out, float* __restrict__ slots) {

  __shared__ __align__(16) float featx[2][16 * 36];  // double-buffered x
  __shared__ __align__(16) float cstate[16 * 36];
  __shared__ __align__(16) float gibuf[16 * 132];    // sigmoid(i) values
  __shared__ __align__(16) float obuf[16 * 36];
  __shared__ __align__(16) float ov1buf[16 * 36];
  __shared__ __align__(16) float mpart[8][16 * 36];  // per-wave m_new r-partials
  __shared__ __align__(16) float isump[128];         // [wave][b] i-gate p-sums
  __shared__ __align__(16) unsigned short tanhb[16 * 72];
  __shared__ __align__(16) unsigned short swzSig[4 * 512];  // GEMM2 B-frags
  __shared__ float s_bvec[64], s_lng[32], s_lnb[32];

  const int tid  = threadIdx.x;
  const int blk  = blockIdx.x;
  const int w    = tid >> 6;
  const int lane = tid & 63;
  const int q    = lane >> 4;
  const int m    = lane & 15;
  const f32v4 z4 = {0.f, 0.f, 0.f, 0.f};

  // ---------------- startup ----------------
  bf16v8 wr0[8], wr1[8];
  float brv[8];
#pragma unroll
  for (int t = 0; t < 8; ++t) {
    const int n = w * 128 + t * 16 + m;
    brv[t] = g_br[n];
#pragma unroll
    for (int kh = 0; kh < 2; ++kh) {
      const float* gp = g_Wr + n * 64 + kh * 32 + q * 8;
      f32v4 u0 = *(const f32v4*)gp;
      f32v4 u1 = *(const f32v4*)(gp + 4);
      bf16v8 fr;
#pragma unroll
      for (int j = 0; j < 4; ++j) { fr[j] = f2b(u0[j]); fr[4 + j] = f2b(u1[j]); }
      if (kh == 0) wr0[t] = fr; else wr1[t] = fr;
    }
  }
  bf16v8 wi0, wi1;
  const float gb = g_bi[w * 16 + m];
  {
    const int n = w * 16 + m;
#pragma unroll
    for (int kh = 0; kh < 2; ++kh) {
      const float* gp = g_Wi + n * 64 + kh * 32 + q * 8;
      f32v4 u0 = *(const f32v4*)gp;
      f32v4 u1 = *(const f32v4*)(gp + 4);
      bf16v8 fr;
#pragma unroll
      for (int j = 0; j < 4; ++j) { fr[j] = f2b(u0[j]); fr[4 + j] = f2b(u1[j]); }
      if (kh == 0) wi0 = fr; else wi1 = fr;
    }
  }
  bf16v8 bo0 = {0,0,0,0,0,0,0,0}, bo1 = bo0, be = bo0;
  float bov = 0.f;
  if (w < 2) {  // W_o B-frags + sigmoid(W_rm^T) frags -> LDS
    const int n = w * 16 + m;
    bov = g_bo[n];
#pragma unroll
    for (int kh = 0; kh < 2; ++kh) {
      bf16v8 fr, fs;
#pragma unroll
      for (int j = 0; j < 8; ++j) {
        fr[j] = f2b(g_Wo[n * 64 + kh * 32 + q * 8 + j]);
        float v = g_Wrm[n * 64 + kh * 32 + q * 8 + j];
        fs[j] = f2b(rcpf(1.0f + __expf(-v)));
      }
      if (kh == 0) bo0 = fr; else bo1 = fr;
      *(bf16v8*)&swzSig[(w * 2 + kh) * 512 + lane * 8] = fs;
    }
  }
  if (w >= 4) {  // exp(W_s) B-frags, K=32 (k = o)
    const int n = (w - 4) * 16 + m;
    bf16v8 fr;
#pragma unroll
    for (int j = 0; j < 8; ++j) fr[j] = f2b(__expf(g_Ws[(q * 8 + j) * 64 + n]));
    be = fr;
  }
  if (tid < 64) {  // bvec[g] = b0 @ exp_Ws  (constant across steps)
    float a = 0.f;
    for (int o = 0; o < 32; ++o) a += g_b0[o] * __expf(g_Ws[o * 64 + tid]);
    s_bvec[tid] = a;
  }
  if (tid < 32) { s_lng[tid] = g_lng[tid]; s_lnb[tid] = g_lnb[tid]; }
  for (int i = tid; i < 16 * 36; i += 512) cstate[i] = 0.0f;
  {  // stage x_0
    const int b2 = tid >> 5, k2 = tid & 31, rg = blk * 16 + b2;
    featx[0][b2 * 36 + k2] =
        (k2 < 4) ? g_xm[rg * 4 + k2] : g_xa[rg * 28 + k2 - 4];
  }
  __syncthreads();
  float bvl = (w >= 4) ? s_bvec[(w - 4) * 16 + m] : 0.f;

  float ph_h = 0, ph_cn = 0, ph_o = 0, ph_MR = 0, ph_op = 0, ph_mrf = 0;
  size_t ph_base = 0;

  // ---------------- time loop ----------------
  for (int s = 0; s < T_STEPS; ++s) {
    // prefetch x_{s+1} — the ONLY pre-spin vmem op (overlaps GEMM1; the poll
    // loop's vmcnt(0) then has at most this nearly-retired load outstanding)
    const int b2 = tid >> 5, k2 = tid & 31;
    const int sp = (s + 1 < T_STEPS) ? s + 1 : T_STEPS - 1;
    const float xv = (k2 < 4)
        ? g_xm[(size_t)sp * 2048 + (blk * 16 + b2) * 4 + k2]
        : g_xa[(size_t)sp * 14336 + (blk * 16 + b2) * 28 + k2 - 4];

    // ---- A-frags (x-half, raw-c-half) ----
    const float* fx = featx[s & 1];
    f32v4 x0 = *(const f32v4*)&fx[m * 36 + q * 8];
    f32v4 x1 = *(const f32v4*)&fx[m * 36 + q * 8 + 4];
    f32v4 c0 = *(const f32v4*)&cstate[m * 36 + q * 8];
    f32v4 c1 = *(const f32v4*)&cstate[m * 36 + q * 8 + 4];
    bf16v8 a0, a1;
#pragma unroll
    for (int j = 0; j < 4; ++j) {
      a0[j] = f2b(x0[j]); a0[4 + j] = f2b(x1[j]);
      a1[j] = f2b(c0[j]); a1[4 + j] = f2b(c1[j]);
    }

    // ---- GEMM1 (all inv-independent; bias seeded via C-operand) ----
    f32v4 rx[8], rc[8];
#pragma unroll
    for (int t = 0; t < 8; ++t) {
      f32v4 cb = {brv[t], brv[t], brv[t], brv[t]};
      rx[t] = __builtin_amdgcn_mfma_f32_16x16x32_bf16(a0, wr0[t], cb, 0, 0, 0);
      rc[t] = __builtin_amdgcn_mfma_f32_16x16x32_bf16(a1, wr1[t], z4, 0, 0, 0);
    }
    f32v4 gxb = {gb, gb, gb, gb};
    f32v4 gxv = __builtin_amdgcn_mfma_f32_16x16x32_bf16(a0, wi0, gxb, 0, 0, 0);
    f32v4 gcv = __builtin_amdgcn_mfma_f32_16x16x32_bf16(a1, wi1, z4, 0, 0, 0);
    f32v4 oxv = z4, ocv = z4, ev = z4;
    if (w < 2) {
      f32v4 ob = {bov, bov, bov, bov};
      oxv = __builtin_amdgcn_mfma_f32_16x16x32_bf16(a0, bo0, ob, 0, 0, 0);
      ocv = __builtin_amdgcn_mfma_f32_16x16x32_bf16(a1, bo1, z4, 0, 0, 0);
    }
    if (w >= 4) {
      ev = __builtin_amdgcn_mfma_f32_16x16x32_bf16(a1, be, z4, 0, 0, 0);
    }
    // c values for the r-contraction (cstate stable until E2)
    f32v4 c4[4];
#pragma unroll
    for (int r = 0; r < 4; ++r)
      c4[r] = *(const f32v4*)&cstate[(q * 4 + r) * 36 + w * 4];

    // ---- spin: all waves poll 256 per-wave partials (4/lane) ----
    float inv_;
    if (s > 0) {
      const float e = ((s >> 1) & 1) ? -1.0f : 1.0f;
      float* sl = slots + (s & 1) * 256 + lane * 4;
      float v0 = 0, v1 = 0, v2 = 0, v3 = 0;
      for (int it = 0; it < (1 << 18); ++it) {
        v0 = __hip_atomic_load(sl + 0, __ATOMIC_RELAXED, __HIP_MEMORY_SCOPE_AGENT);
        v1 = __hip_atomic_load(sl + 1, __ATOMIC_RELAXED, __HIP_MEMORY_SCOPE_AGENT);
        v2 = __hip_atomic_load(sl + 2, __ATOMIC_RELAXED, __HIP_MEMORY_SCOPE_AGENT);
        v3 = __hip_atomic_load(sl + 3, __ATOMIC_RELAXED, __HIP_MEMORY_SCOPE_AGENT);
        if (__all((v0 * e > 0.5f) && (v1 * e > 0.5f) &&
                  (v2 * e > 0.5f) && (v3 * e > 0.5f))) break;
        __builtin_amdgcn_s_sleep(1);
      }
      float sv = (v0 + v1 + v2 + v3) * e - 4.0f;
#pragma unroll
      for (int msk = 1; msk < 64; msk <<= 1) sv += __shfl_xor(sv, msk);
      inv_ = rcpf(sv + 1e-5f);
    } else {
      inv_ = rcpf(1e-5f);
    }

    // ---- post-detect: deferred out-stores for step s-1 + x staging ----
    // (fire-and-forget; acks drain during GEMM2/E2, ~4us before next poll)
    if (s > 0) {
      out[ph_base] = ph_h;
      out[OUTSZ + ph_base] = ph_cn;
      out[2 * OUTSZ + ph_base] = ph_o;
      out[3 * OUTSZ + ph_base] = ph_MR;
      out[4 * OUTSZ + ph_base] = ph_op;
      out[5 * OUTSZ + ph_base] = ph_mrf;
      out[6 * OUTSZ + ph_base] = ph_h;
    }
    featx[(s + 1) & 1][b2 * 36 + k2] = xv;  // read next step after B3

    // ---- post-spin epilogues (short critical path) ----
    if (w >= 4) {  // MR path: tanh(ev*inv - bvec) -> bf16 -> tanhb
#pragma unroll
      for (int r = 0; r < 4; ++r) {
        float t0 = ev[r] * inv_ - bvl;
        float ex = __expf(2.0f * t0);
        float th = 1.0f - 2.0f * rcpf(ex + 1.0f);
        tanhb[(q * 4 + r) * 72 + (w - 4) * 16 + m] = (unsigned short)f2b(th);
      }
    }
    if (w < 2) {  // o-gate
#pragma unroll
      for (int r = 0; r < 4; ++r) {
        float t0 = oxv[r] + ocv[r] * inv_;
        obuf[(q * 4 + r) * 36 + w * 16 + m] = rcpf(1.0f + __expf(-t0));
      }
    }
    {  // i-gate: sigmoid + in-register p-sums
      float sg0, sg1, sg2, sg3;
      {
        float t0 = gxv[0] + gcv[0] * inv_; sg0 = rcpf(1.0f + __expf(-t0));
        t0 = gxv[1] + gcv[1] * inv_; sg1 = rcpf(1.0f + __expf(-t0));
        t0 = gxv[2] + gcv[2] * inv_; sg2 = rcpf(1.0f + __expf(-t0));
        t0 = gxv[3] + gcv[3] * inv_; sg3 = rcpf(1.0f + __expf(-t0));
      }
      gibuf[(q * 4 + 0) * 132 + w * 16 + m] = sg0;
      gibuf[(q * 4 + 1) * 132 + w * 16 + m] = sg1;
      gibuf[(q * 4 + 2) * 132 + w * 16 + m] = sg2;
      gibuf[(q * 4 + 3) * 132 + w * 16 + m] = sg3;
#pragma unroll
      for (int msk = 1; msk < 16; msk <<= 1) {
        sg0 += __shfl_xor(sg0, msk); sg1 += __shfl_xor(sg1, msk);
        sg2 += __shfl_xor(sg2, msk); sg3 += __shfl_xor(sg3, msk);
      }
      if (m == 0) {
        f32v4 sv4 = {sg0, sg1, sg2, sg3};
        *(f32v4*)&isump[w * 16 + q * 4] = sv4;
      }
    }
    {  // r epilogue: combine+relu, row-L1, contract with c
      f32v4 rr[8];
#pragma unroll
      for (int t = 0; t < 8; ++t)
#pragma unroll
        for (int r = 0; r < 4; ++r)
          rr[t][r] = fmaxf(fmaf(rc[t][r], inv_, rx[t][r]), 0.0f);
      float p0[4] = {0, 0, 0, 0}, p1[4] = {0, 0, 0, 0};
#pragma unroll
      for (int ol = 0; ol < 4; ++ol) {
        float s0 = rr[2 * ol][0] + rr[2 * ol + 1][0];
        float s1 = rr[2 * ol][1] + rr[2 * ol + 1][1];
        float s2 = rr[2 * ol][2] + rr[2 * ol + 1][2];
        float s3 = rr[2 * ol][3] + rr[2 * ol + 1][3];
#pragma unroll
        for (int msk = 1; msk < 16; msk <<= 1) {
          s0 += __shfl_xor(s0, msk); s1 += __shfl_xor(s1, msk);
          s2 += __shfl_xor(s2, msk); s3 += __shfl_xor(s3, msk);
        }
        float cr0 = c4[0][ol] * rcpf(fmaxf(s0, 1e-12f));
        float cr1 = c4[1][ol] * rcpf(fmaxf(s1, 1e-12f));
        float cr2 = c4[2][ol] * rcpf(fmaxf(s2, 1e-12f));
        float cr3 = c4[3][ol] * rcpf(fmaxf(s3, 1e-12f));
        p0[0] += rr[2 * ol][0] * cr0; p1[0] += rr[2 * ol + 1][0] * cr0;
        p0[1] += rr[2 * ol][1] * cr1; p1[1] += rr[2 * ol + 1][1] * cr1;
        p0[2] += rr[2 * ol][2] * cr2; p1[2] += rr[2 * ol + 1][2] * cr2;
        p0[3] += rr[2 * ol][3] * cr3; p1[3] += rr[2 * ol + 1][3] * cr3;
      }
#pragma unroll
      for (int r = 0; r < 4; ++r) {
        mpart[w][(q * 4 + r) * 36 + m] = p0[r];
        mpart[w][(q * 4 + r) * 36 + 16 + m] = p1[r];
      }
    }
    __syncthreads();  // B1: tanhb/mpart/gibuf/isump/obuf visible

    if (w < 2) {  // GEMM2: ov1 = tanh(ov0) @ sig_Wr
      bf16v8 a30 = *(const bf16v8*)&tanhb[m * 72 + q * 8];
      bf16v8 a31 = *(const bf16v8*)&tanhb[m * 72 + 32 + q * 8];
      bf16v8 bs0 = *(const bf16v8*)&swzSig[(w * 2 + 0) * 512 + lane * 8];
      bf16v8 bs1 = *(const bf16v8*)&swzSig[(w * 2 + 1) * 512 + lane * 8];
      f32v4 v1v = __builtin_amdgcn_mfma_f32_16x16x32_bf16(a30, bs0, z4, 0, 0, 0);
      v1v = __builtin_amdgcn_mfma_f32_16x16x32_bf16(a31, bs1, v1v, 0, 0, 0);
#pragma unroll
      for (int r = 0; r < 4; ++r)
        ov1buf[(q * 4 + r) * 36 + w * 16 + m] = v1v[r];
    }
    __syncthreads();  // B2

    {  // ---- E2: LN, MR, m_new, state update, publish ----
      const int b = tid >> 5, p = tid & 31;
      float x = ov1buf[b * 36 + p];
      float s1 = x, s2 = x * x;
#pragma unroll
      for (int msk = 1; msk < 32; msk <<= 1) {
        s1 += __shfl_xor(s1, msk); s2 += __shfl_xor(s2, msk);
      }
      float mu = s1 * 0.03125f;
      float var = s2 * 0.03125f - mu * mu;
      float ln = (x - mu) * __builtin_amdgcn_rsqf(fmaxf(var, 0.0f) + 1e-5f) *
                     s_lng[p] + s_lnb[p];
      float o = obuf[b * 36 + p];
      float f = 1.0f - o;
      float MR = fmaxf(fminf(ln, f), f - 1.0f);
      float mn = 0.0f;
#pragma unroll
      for (int w2 = 0; w2 < 8; ++w2) mn += mpart[w2][b * 36 + p];
#pragma unroll
      for (int ii = 0; ii < 4; ++ii) {
        float rsi = rcpf(fmaxf(isump[(2 * ii) * 16 + b] +
                               isump[(2 * ii + 1) * 16 + b], 1e-12f));
        mn += fx[b * 36 + ii] * gibuf[b * 132 + ii * 32 + p] * rsi;
      }
      float op = o + MR;
      ph_h = o * mn;
      ph_cn = (1.0f - op) * mn;
      ph_o = o; ph_MR = MR; ph_op = op;
      ph_mrf = MR * mn;
      ph_base = (size_t)s * 16384 + (size_t)(blk * 16 + b) * 32 + p;
      cstate[b * 36 + p] = ph_cn;
      float aw = fabsf(ph_cn);
#pragma unroll
      for (int msk = 1; msk < 64; msk <<= 1) aw += __shfl_xor(aw, msk);
      if (lane == 0 && s + 1 < T_STEPS) {
        const float tag = (((s + 1) >> 1) & 1) ? -1.0f : 1.0f;
        __hip_atomic_store(slots + ((s + 1) & 1) * 256 + blk * 8 + w,
                           tag * (1.0f + aw), __ATOMIC_RELAXED,
                           __HIP_MEMORY_SCOPE_AGENT);
      }
    }
    __syncthreads();  // B3: cstate + featx for next iteration
  }
  // final stores for s = T_STEPS-1
  out[ph_base] = ph_h;
  out[OUTSZ + ph_base] = ph_cn;
  out[2 * OUTSZ + ph_base] = ph_o;
  out[3 * OUTSZ + ph_base] = ph_MR;
  out[4 * OUTSZ + ph_base] = ph_op;
  out[5 * OUTSZ + ph_base] = ph_mrf;
  out[6 * OUTSZ + ph_base] = ph_h;
}

extern "C" void kernel_launch(void* const* d_in, const int* in_sizes, int n_in,
                              void* d_out, int out_size, void* d_ws, size_t ws_size,
                              hipStream_t stream) {
  (void)in_sizes; (void)n_in; (void)out_size; (void)ws_size;
  const float* xm  = (const float*)d_in[0];
  const float* xa  = (const float*)d_in[1];
  const float* Wi  = (const float*)d_in[2];
  const float* bi  = (const float*)d_in[3];
  const float* Wr  = (const float*)d_in[4];
  const float* br  = (const float*)d_in[5];
  const float* Wo  = (const float*)d_in[6];
  const float* bo  = (const float*)d_in[7];
  const float* Ws  = (const float*)d_in[8];
  const float* Wrm = (const float*)d_in[9];
  const float* b0  = (const float*)d_in[10];
  const float* lng = (const float*)d_in[11];
  const float* lnb = (const float*)d_in[12];
  float* slots = (float*)d_ws;

  // 2-phase slot buffer: 2*256 floats; 0 = not-ready under either sign tag
  hipMemsetAsync(d_ws, 0, 2 * 256 * sizeof(float), stream);
  mclstm_persistent<<<dim3(32), dim3(512), 0, stream>>>(
      xm, xa, Wi, bi, Wr, br, Wo, bo, Ws, Wrm, b0, lng, lnb,
      (float*)d_out, slots);
}

// Round 3
// 2176.651 us; speedup vs baseline: 1.4350x; 1.4350x over previous
//
#include <hip/hip_runtime.h>

// MassConservingLSTM_MR — persistent 32-block recurrent kernel, round 5.
// Base = R2 skeleton (stores at loop top, compact 256-slot all-wave polling —
// both measured best). R5 cuts the in-block detect->publish serial chain:
//  (1) all 16-lane reductions use DPP row_ror chains (VALU, ~7cy/round)
//      instead of __shfl_xor (ds_bpermute, ~45cy/round); 16/32-lane
//      crossings keep one bpermute each.
//  (2) B2 barrier + ov1buf bounce removed: GEMM2 computed redundantly by all
//      waves, result moved MFMA-layout -> tid-layout with 4 bpermutes + 3
//      cndmask selects (C/D mapping: src lane=(b>>2)*16+(p&15), reg=b&3,
//      half=p>>4).
//  (3) launch_bounds(512,1): grid=32 is 1 block/CU anyway; avoid spills.

#define T_STEPS 512
#define OUTSZ 8388608ull  // 512*512*32

using bf16v8 = __attribute__((ext_vector_type(8))) short;
using f32v4  = __attribute__((ext_vector_type(4))) float;

__device__ __forceinline__ short f2b(float f) {
  union { float f; unsigned u; } x; x.f = f;
  unsigned r = x.u + 0x7fffu + ((x.u >> 16) & 1u);
  return (short)(r >> 16);
}
__device__ __forceinline__ float rcpf(float x) { return __builtin_amdgcn_rcpf(x); }

// All-lanes sum within each 16-lane DPP row: 4 rotation rounds, pure VALU.
__device__ __forceinline__ float rowsum16(float v) {
  int t;
  float a = v;
  t = __builtin_amdgcn_mov_dpp(__builtin_bit_cast(int, a), 0x128, 0xF, 0xF, true); // row_ror:8
  a += __builtin_bit_cast(float, t);
  t = __builtin_amdgcn_mov_dpp(__builtin_bit_cast(int, a), 0x124, 0xF, 0xF, true); // row_ror:4
  a += __builtin_bit_cast(float, t);
  t = __builtin_amdgcn_mov_dpp(__builtin_bit_cast(int, a), 0x122, 0xF, 0xF, true); // row_ror:2
  a += __builtin_bit_cast(float, t);
  t = __builtin_amdgcn_mov_dpp(__builtin_bit_cast(int, a), 0x121, 0xF, 0xF, true); // row_ror:1
  a += __builtin_bit_cast(float, t);
  return a;
}

__global__ __launch_bounds__(512, 1) void mclstm_persistent(
    const float* __restrict__ g_xm, const float* __restrict__ g_xa,
    const float* __restrict__ g_Wi, const float* __restrict__ g_bi,
    const float* __restrict__ g_Wr, const float* __restrict__ g_br,
    const float* __restrict__ g_Wo, const float* __restrict__ g_bo,
    const float* __restrict__ g_Ws, const float* __restrict__ g_Wrm,
    const float* __restrict__ g_b0, const float* __restrict__ g_lng,
    const float* __restrict__ g_lnb,
    float* __restrict__ out, float* __restrict__ slots) {

  __shared__ __align__(16) float featx[2][16 * 36];  // double-buffered x
  __shared__ __align__(16) float cstate[16 * 36];
  __shared__ __align__(16) float gibuf[16 * 132];    // sigmoid(i) values
  __shared__ __align__(16) float obuf[16 * 36];
  __shared__ __align__(16) float mpart[8][16 * 36];  // per-wave m_new r-partials
  __shared__ __align__(16) float isump[128];         // [wave][b] i-gate p-sums
  __shared__ __align__(16) unsigned short tanhb[16 * 72];
  __shared__ __align__(16) unsigned short swzSig[4 * 512];  // GEMM2 B-frags
  __shared__ float s_bvec[64], s_lng[32], s_lnb[32];

  const int tid  = threadIdx.x;
  const int blk  = blockIdx.x;
  const int w    = tid >> 6;
  const int lane = tid & 63;
  const int q    = lane >> 4;
  const int m    = lane & 15;
  const f32v4 z4 = {0.f, 0.f, 0.f, 0.f};

  // ---------------- startup ----------------
  bf16v8 wr0[8], wr1[8];
  float brv[8];
#pragma unroll
  for (int t = 0; t < 8; ++t) {
    const int n = w * 128 + t * 16 + m;
    brv[t] = g_br[n];
#pragma unroll
    for (int kh = 0; kh < 2; ++kh) {
      const float* gp = g_Wr + n * 64 + kh * 32 + q * 8;
      f32v4 u0 = *(const f32v4*)gp;
      f32v4 u1 = *(const f32v4*)(gp + 4);
      bf16v8 fr;
#pragma unroll
      for (int j = 0; j < 4; ++j) { fr[j] = f2b(u0[j]); fr[4 + j] = f2b(u1[j]); }
      if (kh == 0) wr0[t] = fr; else wr1[t] = fr;
    }
  }
  bf16v8 wi0, wi1;
  const float gb = g_bi[w * 16 + m];
  {
    const int n = w * 16 + m;
#pragma unroll
    for (int kh = 0; kh < 2; ++kh) {
      const float* gp = g_Wi + n * 64 + kh * 32 + q * 8;
      f32v4 u0 = *(const f32v4*)gp;
      f32v4 u1 = *(const f32v4*)(gp + 4);
      bf16v8 fr;
#pragma unroll
      for (int j = 0; j < 4; ++j) { fr[j] = f2b(u0[j]); fr[4 + j] = f2b(u1[j]); }
      if (kh == 0) wi0 = fr; else wi1 = fr;
    }
  }
  bf16v8 bo0 = {0,0,0,0,0,0,0,0}, bo1 = bo0, be = bo0;
  float bov = 0.f;
  if (w < 2) {  // W_o B-frags + sigmoid(W_rm^T) frags -> LDS
    const int n = w * 16 + m;
    bov = g_bo[n];
#pragma unroll
    for (int kh = 0; kh < 2; ++kh) {
      bf16v8 fr, fs;
#pragma unroll
      for (int j = 0; j < 8; ++j) {
        fr[j] = f2b(g_Wo[n * 64 + kh * 32 + q * 8 + j]);
        float v = g_Wrm[n * 64 + kh * 32 + q * 8 + j];
        fs[j] = f2b(rcpf(1.0f + __expf(-v)));
      }
      if (kh == 0) bo0 = fr; else bo1 = fr;
      *(bf16v8*)&swzSig[(w * 2 + kh) * 512 + lane * 8] = fs;
    }
  }
  if (w >= 4) {  // exp(W_s) B-frags, K=32 (k = o)
    const int n = (w - 4) * 16 + m;
    bf16v8 fr;
#pragma unroll
    for (int j = 0; j < 8; ++j) fr[j] = f2b(__expf(g_Ws[(q * 8 + j) * 64 + n]));
    be = fr;
  }
  if (tid < 64) {  // bvec[g] = b0 @ exp_Ws  (constant across steps)
    float a = 0.f;
    for (int o = 0; o < 32; ++o) a += g_b0[o] * __expf(g_Ws[o * 64 + tid]);
    s_bvec[tid] = a;
  }
  if (tid < 32) { s_lng[tid] = g_lng[tid]; s_lnb[tid] = g_lnb[tid]; }
  for (int i = tid; i < 16 * 36; i += 512) cstate[i] = 0.0f;
  {  // stage x_0
    const int b2 = tid >> 5, k2 = tid & 31, rg = blk * 16 + b2;
    featx[0][b2 * 36 + k2] =
        (k2 < 4) ? g_xm[rg * 4 + k2] : g_xa[rg * 28 + k2 - 4];
  }
  __syncthreads();
  float bvl = (w >= 4) ? s_bvec[(w - 4) * 16 + m] : 0.f;

  float ph_h = 0, ph_cn = 0, ph_o = 0, ph_MR = 0, ph_op = 0, ph_mrf = 0;
  size_t ph_base = 0;

  // ---------------- time loop ----------------
  for (int s = 0; s < T_STEPS; ++s) {
    // deferred out-stores for step s-1 (drain during the spin slack)
    if (s > 0) {
      out[ph_base] = ph_h;
      out[OUTSZ + ph_base] = ph_cn;
      out[2 * OUTSZ + ph_base] = ph_o;
      out[3 * OUTSZ + ph_base] = ph_MR;
      out[4 * OUTSZ + ph_base] = ph_op;
      out[5 * OUTSZ + ph_base] = ph_mrf;
      out[6 * OUTSZ + ph_base] = ph_h;
    }
    // prefetch x_{s+1}
    const int b2 = tid >> 5, k2 = tid & 31;
    const int sp = (s + 1 < T_STEPS) ? s + 1 : T_STEPS - 1;
    const float xv = (k2 < 4)
        ? g_xm[(size_t)sp * 2048 + (blk * 16 + b2) * 4 + k2]
        : g_xa[(size_t)sp * 14336 + (blk * 16 + b2) * 28 + k2 - 4];

    // ---- A-frags (x-half, raw-c-half) ----
    const float* fx = featx[s & 1];
    f32v4 x0 = *(const f32v4*)&fx[m * 36 + q * 8];
    f32v4 x1 = *(const f32v4*)&fx[m * 36 + q * 8 + 4];
    f32v4 c0 = *(const f32v4*)&cstate[m * 36 + q * 8];
    f32v4 c1 = *(const f32v4*)&cstate[m * 36 + q * 8 + 4];
    bf16v8 a0, a1;
#pragma unroll
    for (int j = 0; j < 4; ++j) {
      a0[j] = f2b(x0[j]); a0[4 + j] = f2b(x1[j]);
      a1[j] = f2b(c0[j]); a1[4 + j] = f2b(c1[j]);
    }

    // ---- GEMM1 (all inv-independent; bias seeded via C-operand) ----
    f32v4 rx[8], rc[8];
#pragma unroll
    for (int t = 0; t < 8; ++t) {
      f32v4 cb = {brv[t], brv[t], brv[t], brv[t]};
      rx[t] = __builtin_amdgcn_mfma_f32_16x16x32_bf16(a0, wr0[t], cb, 0, 0, 0);
      rc[t] = __builtin_amdgcn_mfma_f32_16x16x32_bf16(a1, wr1[t], z4, 0, 0, 0);
    }
    f32v4 gxb = {gb, gb, gb, gb};
    f32v4 gxv = __builtin_amdgcn_mfma_f32_16x16x32_bf16(a0, wi0, gxb, 0, 0, 0);
    f32v4 gcv = __builtin_amdgcn_mfma_f32_16x16x32_bf16(a1, wi1, z4, 0, 0, 0);
    f32v4 oxv = z4, ocv = z4, ev = z4;
    if (w < 2) {
      f32v4 ob = {bov, bov, bov, bov};
      oxv = __builtin_amdgcn_mfma_f32_16x16x32_bf16(a0, bo0, ob, 0, 0, 0);
      ocv = __builtin_amdgcn_mfma_f32_16x16x32_bf16(a1, bo1, z4, 0, 0, 0);
    }
    if (w >= 4) {
      ev = __builtin_amdgcn_mfma_f32_16x16x32_bf16(a1, be, z4, 0, 0, 0);
    }
    // c values for the r-contraction (cstate stable until E2)
    f32v4 c4[4];
#pragma unroll
    for (int r = 0; r < 4; ++r)
      c4[r] = *(const f32v4*)&cstate[(q * 4 + r) * 36 + w * 4];
    // stage x_{s+1} (waitcnt absorbed by spin slack)
    featx[(s + 1) & 1][b2 * 36 + k2] = xv;

    // ---- spin: all waves poll 256 per-wave partials (4/lane) ----
    float inv_;
    if (s > 0) {
      const float e = ((s >> 1) & 1) ? -1.0f : 1.0f;
      float* sl = slots + (s & 1) * 256 + lane * 4;
      float v0 = 0, v1 = 0, v2 = 0, v3 = 0;
      for (int it = 0; it < (1 << 18); ++it) {
        v0 = __hip_atomic_load(sl + 0, __ATOMIC_RELAXED, __HIP_MEMORY_SCOPE_AGENT);
        v1 = __hip_atomic_load(sl + 1, __ATOMIC_RELAXED, __HIP_MEMORY_SCOPE_AGENT);
        v2 = __hip_atomic_load(sl + 2, __ATOMIC_RELAXED, __HIP_MEMORY_SCOPE_AGENT);
        v3 = __hip_atomic_load(sl + 3, __ATOMIC_RELAXED, __HIP_MEMORY_SCOPE_AGENT);
        if (__all((v0 * e > 0.5f) && (v1 * e > 0.5f) &&
                  (v2 * e > 0.5f) && (v3 * e > 0.5f))) break;
        __builtin_amdgcn_s_sleep(1);
      }
      float sv = rowsum16((v0 + v1 + v2 + v3) * e - 4.0f);
      sv += __shfl_xor(sv, 16);
      sv += __shfl_xor(sv, 32);
      inv_ = rcpf(sv + 1e-5f);
    } else {
      inv_ = rcpf(1e-5f);
    }

    // ---- post-spin epilogues (short critical path) ----
    if (w >= 4) {  // MR path: tanh(ev*inv - bvec) -> bf16 -> tanhb
#pragma unroll
      for (int r = 0; r < 4; ++r) {
        float t0 = ev[r] * inv_ - bvl;
        float ex = __expf(2.0f * t0);
        float th = 1.0f - 2.0f * rcpf(ex + 1.0f);
        tanhb[(q * 4 + r) * 72 + (w - 4) * 16 + m] = (unsigned short)f2b(th);
      }
    }
    if (w < 2) {  // o-gate
#pragma unroll
      for (int r = 0; r < 4; ++r) {
        float t0 = oxv[r] + ocv[r] * inv_;
        obuf[(q * 4 + r) * 36 + w * 16 + m] = rcpf(1.0f + __expf(-t0));
      }
    }
    {  // i-gate: sigmoid + DPP row-sums
      float sg0, sg1, sg2, sg3;
      {
        float t0 = gxv[0] + gcv[0] * inv_; sg0 = rcpf(1.0f + __expf(-t0));
        t0 = gxv[1] + gcv[1] * inv_; sg1 = rcpf(1.0f + __expf(-t0));
        t0 = gxv[2] + gcv[2] * inv_; sg2 = rcpf(1.0f + __expf(-t0));
        t0 = gxv[3] + gcv[3] * inv_; sg3 = rcpf(1.0f + __expf(-t0));
      }
      gibuf[(q * 4 + 0) * 132 + w * 16 + m] = sg0;
      gibuf[(q * 4 + 1) * 132 + w * 16 + m] = sg1;
      gibuf[(q * 4 + 2) * 132 + w * 16 + m] = sg2;
      gibuf[(q * 4 + 3) * 132 + w * 16 + m] = sg3;
      sg0 = rowsum16(sg0); sg1 = rowsum16(sg1);
      sg2 = rowsum16(sg2); sg3 = rowsum16(sg3);
      if (m == 0) {
        f32v4 sv4 = {sg0, sg1, sg2, sg3};
        *(f32v4*)&isump[w * 16 + q * 4] = sv4;
      }
    }
    {  // r epilogue: combine+relu, DPP row-L1, contract with c
      f32v4 rr[8];
#pragma unroll
      for (int t = 0; t < 8; ++t)
#pragma unroll
        for (int r = 0; r < 4; ++r)
          rr[t][r] = fmaxf(fmaf(rc[t][r], inv_, rx[t][r]), 0.0f);
      float p0[4] = {0, 0, 0, 0}, p1[4] = {0, 0, 0, 0};
#pragma unroll
      for (int ol = 0; ol < 4; ++ol) {
        float s0 = rowsum16(rr[2 * ol][0] + rr[2 * ol + 1][0]);
        float s1 = rowsum16(rr[2 * ol][1] + rr[2 * ol + 1][1]);
        float s2 = rowsum16(rr[2 * ol][2] + rr[2 * ol + 1][2]);
        float s3 = rowsum16(rr[2 * ol][3] + rr[2 * ol + 1][3]);
        float cr0 = c4[0][ol] * rcpf(fmaxf(s0, 1e-12f));
        float cr1 = c4[1][ol] * rcpf(fmaxf(s1, 1e-12f));
        float cr2 = c4[2][ol] * rcpf(fmaxf(s2, 1e-12f));
        float cr3 = c4[3][ol] * rcpf(fmaxf(s3, 1e-12f));
        p0[0] += rr[2 * ol][0] * cr0; p1[0] += rr[2 * ol + 1][0] * cr0;
        p0[1] += rr[2 * ol][1] * cr1; p1[1] += rr[2 * ol + 1][1] * cr1;
        p0[2] += rr[2 * ol][2] * cr2; p1[2] += rr[2 * ol + 1][2] * cr2;
        p0[3] += rr[2 * ol][3] * cr3; p1[3] += rr[2 * ol + 1][3] * cr3;
      }
#pragma unroll
      for (int r = 0; r < 4; ++r) {
        mpart[w][(q * 4 + r) * 36 + m] = p0[r];
        mpart[w][(q * 4 + r) * 36 + 16 + m] = p1[r];
      }
    }
    __syncthreads();  // B1: tanhb/mpart/gibuf/isump/obuf visible

    {  // ---- GEMM2 redundantly in every wave (no B2), then E2 ----
      bf16v8 a30 = *(const bf16v8*)&tanhb[m * 72 + q * 8];
      bf16v8 a31 = *(const bf16v8*)&tanhb[m * 72 + 32 + q * 8];
      bf16v8 b00 = *(const bf16v8*)&swzSig[0 * 512 + lane * 8];
      bf16v8 b01 = *(const bf16v8*)&swzSig[1 * 512 + lane * 8];
      bf16v8 b10 = *(const bf16v8*)&swzSig[2 * 512 + lane * 8];
      bf16v8 b11 = *(const bf16v8*)&swzSig[3 * 512 + lane * 8];
      f32v4 vA = __builtin_amdgcn_mfma_f32_16x16x32_bf16(a30, b00, z4, 0, 0, 0);
      vA = __builtin_amdgcn_mfma_f32_16x16x32_bf16(a31, b01, vA, 0, 0, 0);
      f32v4 vB = __builtin_amdgcn_mfma_f32_16x16x32_bf16(a30, b10, z4, 0, 0, 0);
      vB = __builtin_amdgcn_mfma_f32_16x16x32_bf16(a31, b11, vB, 0, 0, 0);
      // transfer to tid-layout: dest (b,p) = (tid>>5, tid&31);
      // src lane = (b>>2)*16 + (p&15), reg = b&3, half = p>>4
      const int b = tid >> 5, p = tid & 31;
      const int srcl = ((b >> 2) << 4) | (p & 15);
      float x00, x01, x10, x11;
      if ((w & 1) == 0) {  // b&3 in {0,1}, selected by lane>>5
        x00 = __shfl(vA[0], srcl); x01 = __shfl(vB[0], srcl);
        x10 = __shfl(vA[1], srcl); x11 = __shfl(vB[1], srcl);
      } else {             // b&3 in {2,3}
        x00 = __shfl(vA[2], srcl); x01 = __shfl(vB[2], srcl);
        x10 = __shfl(vA[3], srcl); x11 = __shfl(vB[3], srcl);
      }
      const bool hiReg = (lane >> 5) != 0;  // selects b = 2w+1
      const bool hiCol = (p >> 4) != 0;     // selects cols 16-31
      float vh0 = hiReg ? x10 : x00;
      float vh1 = hiReg ? x11 : x01;
      float x = hiCol ? vh1 : vh0;

      // ---- E2: LN, MR, m_new, state update, publish ----
      float s1v = rowsum16(x);      s1v += __shfl_xor(s1v, 16);
      float s2v = rowsum16(x * x);  s2v += __shfl_xor(s2v, 16);
      float mu = s1v * 0.03125f;
      float var = s2v * 0.03125f - mu * mu;
      float ln = (x - mu) * __builtin_amdgcn_rsqf(fmaxf(var, 0.0f) + 1e-5f) *
                     s_lng[p] + s_lnb[p];
      float o = obuf[b * 36 + p];
      float f = 1.0f - o;
      float MR = fmaxf(fminf(ln, f), f - 1.0f);
      float mn = 0.0f;
#pragma unroll
      for (int w2 = 0; w2 < 8; ++w2) mn += mpart[w2][b * 36 + p];
#pragma unroll
      for (int ii = 0; ii < 4; ++ii) {
        float rsi = rcpf(fmaxf(isump[(2 * ii) * 16 + b] +
                               isump[(2 * ii + 1) * 16 + b], 1e-12f));
        mn += fx[b * 36 + ii] * gibuf[b * 132 + ii * 32 + p] * rsi;
      }
      float op = o + MR;
      ph_h = o * mn;
      ph_cn = (1.0f - op) * mn;
      ph_o = o; ph_MR = MR; ph_op = op;
      ph_mrf = MR * mn;
      ph_base = (size_t)s * 16384 + (size_t)(blk * 16 + b) * 32 + p;
      cstate[b * 36 + p] = ph_cn;
      float aw = rowsum16(fabsf(ph_cn));
      aw += __shfl_xor(aw, 16);
      aw += __shfl_xor(aw, 32);
      if (lane == 0 && s + 1 < T_STEPS) {
        const float tag = (((s + 1) >> 1) & 1) ? -1.0f : 1.0f;
        __hip_atomic_store(slots + ((s + 1) & 1) * 256 + blk * 8 + w,
                           tag * (1.0f + aw), __ATOMIC_RELAXED,
                           __HIP_MEMORY_SCOPE_AGENT);
      }
    }
    __syncthreads();  // B3: cstate + featx for next iteration
  }
  // final stores for s = T_STEPS-1
  out[ph_base] = ph_h;
  out[OUTSZ + ph_base] = ph_cn;
  out[2 * OUTSZ + ph_base] = ph_o;
  out[3 * OUTSZ + ph_base] = ph_MR;
  out[4 * OUTSZ + ph_base] = ph_op;
  out[5 * OUTSZ + ph_base] = ph_mrf;
  out[6 * OUTSZ + ph_base] = ph_h;
}

extern "C" void kernel_launch(void* const* d_in, const int* in_sizes, int n_in,
                              void* d_out, int out_size, void* d_ws, size_t ws_size,
                              hipStream_t stream) {
  (void)in_sizes; (void)n_in; (void)out_size; (void)ws_size;
  const float* xm  = (const float*)d_in[0];
  const float* xa  = (const float*)d_in[1];
  const float* Wi  = (const float*)d_in[2];
  const float* bi  = (const float*)d_in[3];
  const float* Wr  = (const float*)d_in[4];
  const float* br  = (const float*)d_in[5];
  const float* Wo  = (const float*)d_in[6];
  const float* bo  = (const float*)d_in[7];
  const float* Ws  = (const float*)d_in[8];
  const float* Wrm = (const float*)d_in[9];
  const float* b0  = (const float*)d_in[10];
  const float* lng = (const float*)d_in[11];
  const float* lnb = (const float*)d_in[12];
  float* slots = (float*)d_ws;

  // 2-phase slot buffer: 2*256 floats; 0 = not-ready under either sign tag
  hipMemsetAsync(d_ws, 0, 2 * 256 * sizeof(float), stream);
  mclstm_persistent<<<dim3(32), dim3(512), 0, stream>>>(
      xm, xa, Wi, bi, Wr, br, Wo, bo, Ws, Wrm, b0, lng, lnb,
      (float*)d_out, slots);
}